// Round 1
// baseline (3139.670 us; speedup 1.0000x reference)
//
#include <hip/hip_runtime.h>
#include <math.h>

// DifferentiableMultiMLPRenderer — fused gather + NeRF-embed + 3-layer MLP + composite.
// B=4, H=W=256 -> 262144 pixels. D_IN=703 (256 feat + 128 shape + 63 emb + 256 style), HID=256.
// Round 0: fp32 vector compute, correctness-first. 16 pixels/block, 256 threads.
// LDS: xs[16][704] (45KB) + h1s[16][256] (16KB); h2 overlays xs (last reader of xs is layer-1).

#define TILE_P 16
#define DIN_PAD 704
#define HID 256
#define FEAT 256
#define SFEAT 128

__global__ __launch_bounds__(256)
void renderer_fused(const int* __restrict__ pix_to_face,
                    const float* __restrict__ bary,
                    const int* __restrict__ faces,
                    const float* __restrict__ feature,
                    const float* __restrict__ shapef,
                    const float* __restrict__ color_bg,
                    const float* __restrict__ style,
                    const float* __restrict__ w1, const float* __restrict__ b1,
                    const float* __restrict__ w2, const float* __restrict__ b2,
                    const float* __restrict__ w3, const float* __restrict__ b3,
                    float* __restrict__ out, int HWtot)
{
    __shared__ float xs[TILE_P][DIN_PAD];
    __shared__ float h1s[TILE_P][HID];
    __shared__ float outv[TILE_P][4];
    float (*h2s)[HID] = reinterpret_cast<float (*)[HID]>(&xs[0][0]);

    const int tid = threadIdx.x;
    const int n0 = blockIdx.x * TILE_P;

    // ---- Phase A: assemble x[p][0..702] in LDS ----
    // layout: [0,256)=feature-blend, [256,384)=shape-blend, [384,447)=nerf_embed(bary), [447,703)=style
    for (int p = 0; p < TILE_P; ++p) {
        const int n = n0 + p;
        const int face = pix_to_face[n];
        const int i0 = faces[face*3+0];
        const int i1 = faces[face*3+1];
        const int i2 = faces[face*3+2];
        const float c0 = bary[n*3+0];
        const float c1 = bary[n*3+1];
        const float c2 = bary[n*3+2];
        const int c = tid;
        if (c < 256) {
            xs[p][c] = (feature[i0*FEAT+c]*c0 + feature[i1*FEAT+c]*c1 + feature[i2*FEAT+c]*c2) * (1.0f/3.0f);
            xs[p][447+c] = style[c];
        }
        if (c < 128)
            xs[p][256+c] = (shapef[i0*SFEAT+c]*c0 + shapef[i1*SFEAT+c]*c1 + shapef[i2*SFEAT+c]*c2) * (1.0f/3.0f);
        if (c < 64) {
            if (c < 3) {
                xs[p][384+c] = (c==0) ? c0 : ((c==1) ? c1 : c2);
            } else if (c < 63) {
                // emb index = 3 + f*6 + s*3 + d; s=0 sin, s=1 cos; freq = 2^f
                const int idx = c - 3;
                const int f = idx / 6;
                const int rem = idx - f*6;
                const int d = (rem >= 3) ? rem - 3 : rem;
                const float bd = (d==0) ? c0 : ((d==1) ? c1 : c2);
                const float arg = bd * (float)(1 << f);
                xs[p][384+c] = (rem < 3) ? sinf(arg) : cosf(arg);
            } else {
                xs[p][703] = 0.0f;  // pad so the float4 k-loop can read k=700..703
            }
        }
    }
    __syncthreads();

    const int lane = tid & 63;
    const int wv = tid >> 6;
    const int j4 = lane << 2;   // 4 hidden units per thread: j4..j4+3
    const int pb = wv << 2;     // 4 pixels per wave: pb..pb+3

    float acc[4][4];  // [pixel][hidden]

    // ---- Layer 1: h1 = relu(x @ w1 + b1), w1 is [703][256] row-major ----
    {
        const float4 bb = *(const float4*)(b1 + j4);
        #pragma unroll
        for (int pp = 0; pp < 4; ++pp) { acc[pp][0]=bb.x; acc[pp][1]=bb.y; acc[pp][2]=bb.z; acc[pp][3]=bb.w; }
        for (int k = 0; k < 700; k += 4) {
            const float4 wa = *(const float4*)(w1 + (k+0)*HID + j4);
            const float4 wb = *(const float4*)(w1 + (k+1)*HID + j4);
            const float4 wc = *(const float4*)(w1 + (k+2)*HID + j4);
            const float4 wd = *(const float4*)(w1 + (k+3)*HID + j4);
            #pragma unroll
            for (int pp = 0; pp < 4; ++pp) {
                const float4 xv = *(const float4*)(&xs[pb+pp][k]);
                acc[pp][0] += xv.x*wa.x + xv.y*wb.x + xv.z*wc.x + xv.w*wd.x;
                acc[pp][1] += xv.x*wa.y + xv.y*wb.y + xv.z*wc.y + xv.w*wd.y;
                acc[pp][2] += xv.x*wa.z + xv.y*wb.z + xv.z*wc.z + xv.w*wd.z;
                acc[pp][3] += xv.x*wa.w + xv.y*wb.w + xv.z*wc.w + xv.w*wd.w;
            }
        }
        for (int k = 700; k < 703; ++k) {
            const float4 wa = *(const float4*)(w1 + k*HID + j4);
            #pragma unroll
            for (int pp = 0; pp < 4; ++pp) {
                const float xv = xs[pb+pp][k];
                acc[pp][0] += xv*wa.x; acc[pp][1] += xv*wa.y;
                acc[pp][2] += xv*wa.z; acc[pp][3] += xv*wa.w;
            }
        }
        #pragma unroll
        for (int pp = 0; pp < 4; ++pp) {
            float4 hv;
            hv.x = fmaxf(acc[pp][0], 0.0f);
            hv.y = fmaxf(acc[pp][1], 0.0f);
            hv.z = fmaxf(acc[pp][2], 0.0f);
            hv.w = fmaxf(acc[pp][3], 0.0f);
            *(float4*)(&h1s[pb+pp][j4]) = hv;
        }
    }
    __syncthreads();  // all layer-1 reads of xs complete; xs region reusable as h2

    // ---- Layer 2: h2 = relu(h1 @ w2 + b2), w2 is [256][256] ----
    {
        const float4 bb = *(const float4*)(b2 + j4);
        #pragma unroll
        for (int pp = 0; pp < 4; ++pp) { acc[pp][0]=bb.x; acc[pp][1]=bb.y; acc[pp][2]=bb.z; acc[pp][3]=bb.w; }
        for (int k = 0; k < HID; k += 4) {
            const float4 wa = *(const float4*)(w2 + (k+0)*HID + j4);
            const float4 wb = *(const float4*)(w2 + (k+1)*HID + j4);
            const float4 wc = *(const float4*)(w2 + (k+2)*HID + j4);
            const float4 wd = *(const float4*)(w2 + (k+3)*HID + j4);
            #pragma unroll
            for (int pp = 0; pp < 4; ++pp) {
                const float4 xv = *(const float4*)(&h1s[pb+pp][k]);
                acc[pp][0] += xv.x*wa.x + xv.y*wb.x + xv.z*wc.x + xv.w*wd.x;
                acc[pp][1] += xv.x*wa.y + xv.y*wb.y + xv.z*wc.y + xv.w*wd.y;
                acc[pp][2] += xv.x*wa.z + xv.y*wb.z + xv.z*wc.z + xv.w*wd.z;
                acc[pp][3] += xv.x*wa.w + xv.y*wb.w + xv.z*wc.w + xv.w*wd.w;
            }
        }
        #pragma unroll
        for (int pp = 0; pp < 4; ++pp) {
            float4 hv;
            hv.x = fmaxf(acc[pp][0], 0.0f);
            hv.y = fmaxf(acc[pp][1], 0.0f);
            hv.z = fmaxf(acc[pp][2], 0.0f);
            hv.w = fmaxf(acc[pp][3], 0.0f);
            *(float4*)(&h2s[pb+pp][j4]) = hv;
        }
    }
    __syncthreads();

    // ---- Layer 3: out = relu(h2 @ w3 + b3) - 1 ; w3 is [256][3] ----
    if (tid < TILE_P * 3) {
        const int p = tid / 3, o = tid - 3*(tid/3);
        float a = b3[o];
        for (int k = 0; k < HID; ++k) a += h2s[p][k] * w3[k*3+o];
        outv[p][o] = fmaxf(a, 0.0f) - 1.0f;
    }
    __syncthreads();

    // ---- Composite + write [B,H,W,4] ----
    if (tid < TILE_P * 4) {
        const int p = tid >> 2, ch = tid & 3;
        const int n = n0 + p;
        const int b = n >> 16;  // H*W = 65536
        const bool m = pix_to_face[n] > 0;
        float v;
        if (ch == 3)      v = m ? 1.0f : 0.0f;
        else              v = m ? outv[p][ch] : color_bg[b*3+ch];
        out[n*4+ch] = v;
    }
}

extern "C" void kernel_launch(void* const* d_in, const int* in_sizes, int n_in,
                              void* d_out, int out_size, void* d_ws, size_t ws_size,
                              hipStream_t stream) {
    const int*   pix_to_face = (const int*)  d_in[0];
    const float* bary        = (const float*)d_in[1];
    const int*   faces       = (const int*)  d_in[2];
    const float* feature     = (const float*)d_in[3];
    const float* shapef      = (const float*)d_in[4];
    const float* color_bg    = (const float*)d_in[5];
    const float* style       = (const float*)d_in[6];
    const float* w1          = (const float*)d_in[7];
    const float* b1          = (const float*)d_in[8];
    const float* w2          = (const float*)d_in[9];
    const float* b2          = (const float*)d_in[10];
    const float* w3          = (const float*)d_in[11];
    const float* b3          = (const float*)d_in[12];
    float* out = (float*)d_out;

    const int npix = in_sizes[0];            // 262144
    const int grid = npix / TILE_P;          // 16384 blocks

    hipLaunchKernelGGL(renderer_fused, dim3(grid), dim3(256), 0, stream,
                       pix_to_face, bary, faces, feature, shapef, color_bg, style,
                       w1, b1, w2, b2, w3, b3, out, npix);
}

// Round 2
// 514.641 us; speedup vs baseline: 6.1007x; 6.1007x over previous
//
#include <hip/hip_runtime.h>
#include <math.h>

// DifferentiableMultiMLPRenderer — bf16-MFMA fused renderer.
// Key facts: style block of x is constant -> folded into b1 (K1: 703->448).
// Layer1: X[64][448] @ W1[448][256]; Layer2: H1[64][256] @ W2[256][256]; both MFMA.
// Layer3 (256->3) + composite on VALU.

typedef __attribute__((ext_vector_type(8))) short short8;
typedef __attribute__((ext_vector_type(4))) float f32x4;

#define TILE_M 64
#define XS_STR 456   // 448 + pad; stride 912B: 16B-aligned, 2-way bank max
#define H1_STR 264   // 256 + pad; 528B: 16B-aligned, 2-way
#define WT_STR 40    // 32 + pad; 80B: 16B-aligned, 2-way
#define NKT1 14      // 448/32
#define NKT2 8       // 256/32
#define NT (NKT1 + NKT2)

__device__ inline unsigned short f2b(float f) {
    unsigned int u = __builtin_bit_cast(unsigned int, f);
    u += 0x7fffu + ((u >> 16) & 1u);           // RNE
    return (unsigned short)(u >> 16);
}
__device__ inline float b2f(unsigned short h) {
    unsigned int u = ((unsigned int)h) << 16;
    return __builtin_bit_cast(float, u);
}

// ---- prep: fold style into bias; build bf16 transposed weights in ws ----
__global__ __launch_bounds__(256)
void prep_weights(const float* __restrict__ style,
                  const float* __restrict__ w1, const float* __restrict__ b1,
                  const float* __restrict__ w2,
                  unsigned short* __restrict__ w1T, unsigned short* __restrict__ w2T,
                  float* __restrict__ b1p)
{
    const int j = blockIdx.x;
    const int t = threadIdx.x;
    if (j < 256) {
        // b1p[j] = b1[j] + sum_k style[k] * w1[447+k][j]   (fp32 exact)
        float part = style[t] * w1[(size_t)(447 + t) * 256 + j];
        #pragma unroll
        for (int off = 32; off; off >>= 1) part += __shfl_down(part, off, 64);
        __shared__ float red[4];
        if ((t & 63) == 0) red[t >> 6] = part;
        __syncthreads();
        if (t == 0) b1p[j] = b1[j] + red[0] + red[1] + red[2] + red[3];
        // w1T[j][k] = bf16(w1[k][j]), k<447; pad k=447 with 0
        for (int k = t; k < 448; k += 256)
            w1T[(size_t)j * 448 + k] = (k < 447) ? f2b(w1[(size_t)k * 256 + j]) : (unsigned short)0;
    } else {
        const int jj = j - 256;
        w2T[(size_t)jj * 256 + t] = f2b(w2[(size_t)t * 256 + jj]);
    }
}

// ---- main fused kernel ----
__global__ __launch_bounds__(512)
void renderer_mfma(const int* __restrict__ pix, const float* __restrict__ bary,
                   const int* __restrict__ faces,
                   const float* __restrict__ feature, const float* __restrict__ shapef,
                   const float* __restrict__ color_bg,
                   const float* __restrict__ b2g,
                   const float* __restrict__ w3, const float* __restrict__ b3,
                   const unsigned short* __restrict__ w1T,
                   const unsigned short* __restrict__ w2T,
                   const float* __restrict__ b1p,
                   float* __restrict__ out)
{
    __shared__ unsigned short xs[TILE_M * XS_STR];   // 58,368 B (also reused as h2s)
    __shared__ unsigned short h1s[TILE_M * H1_STR];  // 33,792 B
    __shared__ unsigned short wt[256 * WT_STR];      // 20,480 B
    __shared__ int   vidx[TILE_M][3];
    __shared__ float bcs[TILE_M][3];

    const int tid  = threadIdx.x;
    const int n0   = blockIdx.x * TILE_M;
    const int lane = tid & 63;
    const int wv   = tid >> 6;
    const int mbase = (wv >> 2) * 32;
    const int nbase = (wv & 3) * 64;
    const int l15  = lane & 15;
    const int kq   = lane >> 4;          // 0..3

    // staging: thread covers 16 bf16 (32B) of one weight column per tile
    const int sj = tid >> 1;
    const int sk = (tid & 1) * 16;
    uint4 r0, r1;
    {   // prefetch tile 0 (w1T, kt=0) — overlaps the whole gather phase
        const uint4* p = (const uint4*)(w1T + (size_t)sj * 448 + sk);
        r0 = p[0]; r1 = p[1];
    }

    // phase 0: per-pixel scalars
    if (tid < TILE_M) {
        const int n = n0 + tid;
        const int face = pix[n];
        vidx[tid][0] = faces[face * 3 + 0];
        vidx[tid][1] = faces[face * 3 + 1];
        vidx[tid][2] = faces[face * 3 + 2];
        bcs[tid][0] = bary[n * 3 + 0];
        bcs[tid][1] = bary[n * 3 + 1];
        bcs[tid][2] = bary[n * 3 + 2];
    }
    __syncthreads();

    // phase A1: feature gather+blend -> xs[p][0..255]
    {
        const int c4 = (tid & 63) << 2;
        const int pg = tid >> 6;
        #pragma unroll
        for (int pp = 0; pp < 8; ++pp) {
            const int p = (pp << 3) + pg;
            const int i0 = vidx[p][0], i1 = vidx[p][1], i2 = vidx[p][2];
            const float c0 = bcs[p][0], c1 = bcs[p][1], c2 = bcs[p][2];
            const float4 f0 = *(const float4*)(feature + (size_t)i0 * 256 + c4);
            const float4 f1 = *(const float4*)(feature + (size_t)i1 * 256 + c4);
            const float4 f2 = *(const float4*)(feature + (size_t)i2 * 256 + c4);
            const float vx = (f0.x*c0 + f1.x*c1 + f2.x*c2) * (1.0f/3.0f);
            const float vy = (f0.y*c0 + f1.y*c1 + f2.y*c2) * (1.0f/3.0f);
            const float vz = (f0.z*c0 + f1.z*c1 + f2.z*c2) * (1.0f/3.0f);
            const float vw = (f0.w*c0 + f1.w*c1 + f2.w*c2) * (1.0f/3.0f);
            uint2 pk;
            pk.x = (unsigned int)f2b(vx) | ((unsigned int)f2b(vy) << 16);
            pk.y = (unsigned int)f2b(vz) | ((unsigned int)f2b(vw) << 16);
            *(uint2*)(&xs[p * XS_STR + c4]) = pk;
        }
    }
    // phase A2: shape gather+blend -> xs[p][256..383]
    {
        const int c4 = (tid & 31) << 2;
        const int pg = tid >> 5;
        #pragma unroll
        for (int pp = 0; pp < 4; ++pp) {
            const int p = (pp << 4) + pg;
            const int i0 = vidx[p][0], i1 = vidx[p][1], i2 = vidx[p][2];
            const float c0 = bcs[p][0], c1 = bcs[p][1], c2 = bcs[p][2];
            const float4 f0 = *(const float4*)(shapef + (size_t)i0 * 128 + c4);
            const float4 f1 = *(const float4*)(shapef + (size_t)i1 * 128 + c4);
            const float4 f2 = *(const float4*)(shapef + (size_t)i2 * 128 + c4);
            const float vx = (f0.x*c0 + f1.x*c1 + f2.x*c2) * (1.0f/3.0f);
            const float vy = (f0.y*c0 + f1.y*c1 + f2.y*c2) * (1.0f/3.0f);
            const float vz = (f0.z*c0 + f1.z*c1 + f2.z*c2) * (1.0f/3.0f);
            const float vw = (f0.w*c0 + f1.w*c1 + f2.w*c2) * (1.0f/3.0f);
            uint2 pk;
            pk.x = (unsigned int)f2b(vx) | ((unsigned int)f2b(vy) << 16);
            pk.y = (unsigned int)f2b(vz) | ((unsigned int)f2b(vw) << 16);
            *(uint2*)(&xs[p * XS_STR + 256 + c4]) = pk;
        }
    }
    // phase A3: NeRF embed -> xs[p][384..447] (slot 63 = pad 0)
    {
        const int p = tid >> 3;
        const int e = tid & 7;
        const float c0 = bcs[p][0], c1 = bcs[p][1], c2 = bcs[p][2];
        #pragma unroll
        for (int i = 0; i < 8; ++i) {
            const int s = e * 8 + i;
            float v;
            if (s < 3) v = (s == 0) ? c0 : ((s == 1) ? c1 : c2);
            else if (s < 63) {
                const int q = s - 3;
                const int f = q / 6;
                const int rem = q - f * 6;
                const int d = (rem >= 3) ? rem - 3 : rem;
                const float bd = (d == 0) ? c0 : ((d == 1) ? c1 : c2);
                const float arg = bd * (float)(1 << f);
                v = (rem < 3) ? sinf(arg) : cosf(arg);
            } else v = 0.0f;
            xs[p * XS_STR + 384 + s] = f2b(v);
        }
    }

    // acc init with folded bias
    f32x4 acc[2][4];
    #pragma unroll
    for (int nf = 0; nf < 4; ++nf) {
        const float b = b1p[nbase + nf * 16 + l15];
        acc[0][nf] = (f32x4){b, b, b, b};
        acc[1][nf] = acc[0][nf];
    }

    // unified 22-tile K-loop: tiles 0..13 = layer1 (A=xs), 14..21 = layer2 (A=h1s)
    for (int t = 0; t < NT; ++t) {
        __syncthreads();                       // wt free / (t==0) xs ready
        { uint4* d = (uint4*)&wt[sj * WT_STR + sk]; d[0] = r0; d[1] = r1; }
        if (t + 1 < NT) {                      // prefetch next tile into regs
            const unsigned short* src; int kstr, kt;
            if (t + 1 < NKT1) { src = w1T; kstr = 448; kt = t + 1; }
            else             { src = w2T; kstr = 256; kt = t + 1 - NKT1; }
            const uint4* p = (const uint4*)(src + (size_t)sj * kstr + kt * 32 + sk);
            r0 = p[0]; r1 = p[1];
        }
        __syncthreads();                       // wt ready

        const unsigned short* asrc; int astr, kbase;
        if (t < NKT1) { asrc = xs;  astr = XS_STR; kbase = t * 32; }
        else          { asrc = h1s; astr = H1_STR; kbase = (t - NKT1) * 32; }

        short8 av[2], bv[4];
        #pragma unroll
        for (int mf = 0; mf < 2; ++mf)
            av[mf] = *(const short8*)(asrc + (mbase + mf * 16 + l15) * astr + kbase + (kq << 3));
        #pragma unroll
        for (int nf = 0; nf < 4; ++nf)
            bv[nf] = *(const short8*)(wt + (nbase + nf * 16 + l15) * WT_STR + (kq << 3));
        #pragma unroll
        for (int mf = 0; mf < 2; ++mf)
            #pragma unroll
            for (int nf = 0; nf < 4; ++nf)
                acc[mf][nf] = __builtin_amdgcn_mfma_f32_16x16x32_bf16(av[mf], bv[nf], acc[mf][nf], 0, 0, 0);

        if (t == NKT1 - 1) {                   // end of layer 1: relu -> h1s, re-init acc
            #pragma unroll
            for (int mf = 0; mf < 2; ++mf)
                #pragma unroll
                for (int nf = 0; nf < 4; ++nf) {
                    const int col  = nbase + nf * 16 + l15;
                    const int row0 = mbase + mf * 16 + (kq << 2);
                    #pragma unroll
                    for (int r = 0; r < 4; ++r)
                        h1s[(row0 + r) * H1_STR + col] = f2b(fmaxf(acc[mf][nf][r], 0.0f));
                    const float b = b2g[col];
                    acc[mf][nf] = (f32x4){b, b, b, b};
                }
        }
    }

    // layer-2 output: relu -> h2s (overlays xs; all xs reads long done)
    unsigned short* h2s = xs;
    #pragma unroll
    for (int mf = 0; mf < 2; ++mf)
        #pragma unroll
        for (int nf = 0; nf < 4; ++nf) {
            const int col  = nbase + nf * 16 + l15;
            const int row0 = mbase + mf * 16 + (kq << 2);
            #pragma unroll
            for (int r = 0; r < 4; ++r)
                h2s[(row0 + r) * H1_STR + col] = f2b(fmaxf(acc[mf][nf][r], 0.0f));
        }
    __syncthreads();

    // layer 3 (256->3) + composite
    if (tid < 192) {
        const int p = tid / 3;
        const int o = tid - p * 3;
        const unsigned short* hrow = h2s + p * H1_STR;
        float a = b3[o];
        for (int k = 0; k < 256; k += 4) {
            a += b2f(hrow[k + 0]) * w3[(k + 0) * 3 + o];
            a += b2f(hrow[k + 1]) * w3[(k + 1) * 3 + o];
            a += b2f(hrow[k + 2]) * w3[(k + 2) * 3 + o];
            a += b2f(hrow[k + 3]) * w3[(k + 3) * 3 + o];
        }
        const float v = fmaxf(a, 0.0f) - 1.0f;
        const int n = n0 + p;
        const int b = n >> 16;                  // H*W = 65536
        const bool m = pix[n] > 0;
        out[(size_t)n * 4 + o] = m ? v : color_bg[b * 3 + o];
    } else if (tid < 256) {
        const int p = tid - 192;
        const int n = n0 + p;
        out[(size_t)n * 4 + 3] = (pix[n] > 0) ? 1.0f : 0.0f;
    }
}

extern "C" void kernel_launch(void* const* d_in, const int* in_sizes, int n_in,
                              void* d_out, int out_size, void* d_ws, size_t ws_size,
                              hipStream_t stream) {
    const int*   pix      = (const int*)  d_in[0];
    const float* bary     = (const float*)d_in[1];
    const int*   faces    = (const int*)  d_in[2];
    const float* feature  = (const float*)d_in[3];
    const float* shapef   = (const float*)d_in[4];
    const float* color_bg = (const float*)d_in[5];
    const float* style    = (const float*)d_in[6];
    const float* w1       = (const float*)d_in[7];
    const float* b1       = (const float*)d_in[8];
    const float* w2       = (const float*)d_in[9];
    const float* b2       = (const float*)d_in[10];
    const float* w3       = (const float*)d_in[11];
    const float* b3       = (const float*)d_in[12];
    float* out = (float*)d_out;

    unsigned short* w1T = (unsigned short*)d_ws;              // 256*448 bf16
    unsigned short* w2T = w1T + 256 * 448;                    // 256*256 bf16
    float*          b1p = (float*)(w2T + 256 * 256);          // 256 f32

    hipLaunchKernelGGL(prep_weights, dim3(512), dim3(256), 0, stream,
                       style, w1, b1, w2, w1T, w2T, b1p);

    const int npix = in_sizes[0];                             // 262144
    hipLaunchKernelGGL(renderer_mfma, dim3(npix / TILE_M), dim3(512), 0, stream,
                       pix, bary, faces, feature, shapef, color_bg,
                       b2, w3, b3, w1T, w2T, b1p, out);
}

// Round 3
// 454.094 us; speedup vs baseline: 6.9141x; 1.1333x over previous
//
#include <hip/hip_runtime.h>
#include <math.h>

// DifferentiableMultiMLPRenderer — bf16-MFMA fused renderer, round 3.
// Structure: style folded into b1 (K1 703->448). TILE_M=32 px/block, 256 thr (4 waves,
// wave-tile 32x64). Weights read直接 from global (L2-resident) with 2-deep register
// double-buffer -> barrier-free 22-tile K-loop. xs XOR-swizzled, h1/h2 overlay xs.

typedef __attribute__((ext_vector_type(8))) short short8;
typedef __attribute__((ext_vector_type(4))) float f32x4;

#define TILE_M 32
#define NKT1 14      // 448/32 layer-1 K-tiles
#define NKT2 8       // 256/32 layer-2 K-tiles
#define NT (NKT1 + NKT2)

__device__ inline unsigned short f2b(float f) {
    unsigned int u = __builtin_bit_cast(unsigned int, f);
    u += 0x7fffu + ((u >> 16) & 1u);           // RNE
    return (unsigned short)(u >> 16);
}
__device__ inline float b2f(unsigned short h) {
    unsigned int u = ((unsigned int)h) << 16;
    return __builtin_bit_cast(float, u);
}
// xs swizzle: 16B granules XOR'd by row&7 -> conflict-free ds_read_b128 at stride 448
__device__ inline int swz(int row, int k) {
    return row * 448 + ((((k >> 3) ^ (row & 7)) << 3) | (k & 7));
}

// ---- prep: fold style into bias; build bf16 transposed weights in ws ----
__global__ __launch_bounds__(256)
void prep_weights(const float* __restrict__ style,
                  const float* __restrict__ w1, const float* __restrict__ b1,
                  const float* __restrict__ w2,
                  unsigned short* __restrict__ w1T, unsigned short* __restrict__ w2T,
                  float* __restrict__ b1p)
{
    const int j = blockIdx.x;
    const int t = threadIdx.x;
    if (j < 256) {
        float part = style[t] * w1[(size_t)(447 + t) * 256 + j];
        #pragma unroll
        for (int off = 32; off; off >>= 1) part += __shfl_down(part, off, 64);
        __shared__ float red[4];
        if ((t & 63) == 0) red[t >> 6] = part;
        __syncthreads();
        if (t == 0) b1p[j] = b1[j] + red[0] + red[1] + red[2] + red[3];
        for (int k = t; k < 448; k += 256)
            w1T[(size_t)j * 448 + k] = (k < 447) ? f2b(w1[(size_t)k * 256 + j]) : (unsigned short)0;
    } else {
        const int jj = j - 256;
        w2T[(size_t)jj * 256 + t] = f2b(w2[(size_t)t * 256 + jj]);
    }
}

// ---- main fused kernel ----
__global__ __launch_bounds__(256, 4)
void renderer_mfma(const int* __restrict__ pix, const float* __restrict__ bary,
                   const int* __restrict__ faces,
                   const float* __restrict__ feature, const float* __restrict__ shapef,
                   const float* __restrict__ color_bg,
                   const float* __restrict__ b2g,
                   const float* __restrict__ w3, const float* __restrict__ b3,
                   const unsigned short* __restrict__ w1T,
                   const unsigned short* __restrict__ w2T,
                   const float* __restrict__ b1p,
                   float* __restrict__ out)
{
    __shared__ unsigned short xs[TILE_M * 448];   // 28,672 B; h1/h2 overlay cols 0..255
    __shared__ int   vidx[TILE_M][3];
    __shared__ float bcs[TILE_M][3];

    const int tid  = threadIdx.x;
    // XCD-aware bijective swizzle (grid = 8192, divisible by 8)
    const int cpx = gridDim.x >> 3;
    const int bid = (blockIdx.x & 7) * cpx + (blockIdx.x >> 3);
    const int n0  = bid * TILE_M;

    const int lane  = tid & 63;
    const int wv    = tid >> 6;          // 4 waves, all n-groups (mbase = 0)
    const int nbase = wv << 6;           // 64 cols per wave
    const int l15   = lane & 15;
    const int kq    = lane >> 4;         // 0..3

    // B-fragment global pointers (short8 units), per nf column group
    const short8* bp1[4];
    const short8* bp2[4];
    #pragma unroll
    for (int nf = 0; nf < 4; ++nf) {
        const int col = nbase + nf * 16 + l15;
        bp1[nf] = (const short8*)(w1T + (size_t)col * 448 + (kq << 3));
        bp2[nf] = (const short8*)(w2T + (size_t)col * 256 + (kq << 3));
    }
    // prefetch tiles 0 and 1 — overlaps the whole gather phase
    short8 bv0[4], bv1[4];
    #pragma unroll
    for (int nf = 0; nf < 4; ++nf) bv0[nf] = bp1[nf][0];
    #pragma unroll
    for (int nf = 0; nf < 4; ++nf) bv1[nf] = bp1[nf][4];

    // phase 0: per-pixel scalars
    if (tid < TILE_M) {
        const int n = n0 + tid;
        const int face = pix[n];
        vidx[tid][0] = faces[face * 3 + 0];
        vidx[tid][1] = faces[face * 3 + 1];
        vidx[tid][2] = faces[face * 3 + 2];
        bcs[tid][0] = bary[n * 3 + 0];
        bcs[tid][1] = bary[n * 3 + 1];
        bcs[tid][2] = bary[n * 3 + 2];
    }
    __syncthreads();

    // phase A1: feature gather+blend -> xs[p][0..255]
    {
        const int c4 = (tid & 63) << 2;
        const int pg = tid >> 6;
        #pragma unroll
        for (int pp = 0; pp < 8; ++pp) {
            const int p = (pp << 2) + pg;
            const int i0 = vidx[p][0], i1 = vidx[p][1], i2 = vidx[p][2];
            const float c0 = bcs[p][0], c1 = bcs[p][1], c2 = bcs[p][2];
            const float4 f0 = *(const float4*)(feature + (size_t)i0 * 256 + c4);
            const float4 f1 = *(const float4*)(feature + (size_t)i1 * 256 + c4);
            const float4 f2 = *(const float4*)(feature + (size_t)i2 * 256 + c4);
            const float vx = (f0.x*c0 + f1.x*c1 + f2.x*c2) * (1.0f/3.0f);
            const float vy = (f0.y*c0 + f1.y*c1 + f2.y*c2) * (1.0f/3.0f);
            const float vz = (f0.z*c0 + f1.z*c1 + f2.z*c2) * (1.0f/3.0f);
            const float vw = (f0.w*c0 + f1.w*c1 + f2.w*c2) * (1.0f/3.0f);
            uint2 pk;
            pk.x = (unsigned int)f2b(vx) | ((unsigned int)f2b(vy) << 16);
            pk.y = (unsigned int)f2b(vz) | ((unsigned int)f2b(vw) << 16);
            *(uint2*)(&xs[swz(p, c4)]) = pk;
        }
    }
    // phase A2: shape gather+blend -> xs[p][256..383]
    {
        const int c4 = (tid & 31) << 2;
        const int pg = tid >> 5;
        #pragma unroll
        for (int pp = 0; pp < 4; ++pp) {
            const int p = (pp << 3) + pg;
            const int i0 = vidx[p][0], i1 = vidx[p][1], i2 = vidx[p][2];
            const float c0 = bcs[p][0], c1 = bcs[p][1], c2 = bcs[p][2];
            const float4 f0 = *(const float4*)(shapef + (size_t)i0 * 128 + c4);
            const float4 f1 = *(const float4*)(shapef + (size_t)i1 * 128 + c4);
            const float4 f2 = *(const float4*)(shapef + (size_t)i2 * 128 + c4);
            const float vx = (f0.x*c0 + f1.x*c1 + f2.x*c2) * (1.0f/3.0f);
            const float vy = (f0.y*c0 + f1.y*c1 + f2.y*c2) * (1.0f/3.0f);
            const float vz = (f0.z*c0 + f1.z*c1 + f2.z*c2) * (1.0f/3.0f);
            const float vw = (f0.w*c0 + f1.w*c1 + f2.w*c2) * (1.0f/3.0f);
            uint2 pk;
            pk.x = (unsigned int)f2b(vx) | ((unsigned int)f2b(vy) << 16);
            pk.y = (unsigned int)f2b(vz) | ((unsigned int)f2b(vw) << 16);
            *(uint2*)(&xs[swz(p, 256 + c4)]) = pk;
        }
    }
    // phase A3: NeRF embed -> xs[p][384..447] (slot 63 = pad 0)
    {
        const int p = tid >> 3;
        const int e = tid & 7;
        const float c0 = bcs[p][0], c1 = bcs[p][1], c2 = bcs[p][2];
        #pragma unroll
        for (int i = 0; i < 8; ++i) {
            const int s = e * 8 + i;
            float v;
            if (s < 3) v = (s == 0) ? c0 : ((s == 1) ? c1 : c2);
            else if (s < 63) {
                const int q = s - 3;
                const int f = q / 6;
                const int rem = q - f * 6;
                const int d = (rem >= 3) ? rem - 3 : rem;
                const float bd = (d == 0) ? c0 : ((d == 1) ? c1 : c2);
                const float arg = bd * (float)(1 << f);
                v = (rem < 3) ? sinf(arg) : cosf(arg);
            } else v = 0.0f;
            xs[swz(p, 384 + s)] = f2b(v);
        }
    }

    // acc init with folded bias
    f32x4 acc[2][4];
    #pragma unroll
    for (int nf = 0; nf < 4; ++nf) {
        const float b = b1p[nbase + nf * 16 + l15];
        acc[0][nf] = (f32x4){b, b, b, b};
        acc[1][nf] = acc[0][nf];
    }
    __syncthreads();   // xs ready

    // barrier-free 22-tile K-loop (fully unrolled; static buffer parity)
    auto tile_step = [&](const int t, short8* bv) {
        if (t == NKT1) {
            __syncthreads();   // all layer-1 A-reads done
            #pragma unroll
            for (int mf = 0; mf < 2; ++mf)
                #pragma unroll
                for (int nf = 0; nf < 4; ++nf) {
                    const int col  = nbase + nf * 16 + l15;
                    const int row0 = mf * 16 + (kq << 2);
                    #pragma unroll
                    for (int r = 0; r < 4; ++r)
                        xs[swz(row0 + r, col)] = f2b(fmaxf(acc[mf][nf][r], 0.0f));
                    const float b = b2g[col];
                    acc[mf][nf] = (f32x4){b, b, b, b};
                }
            __syncthreads();   // h1 visible
        }
        const int kb = (t < NKT1) ? (t << 5) : ((t - NKT1) << 5);
        const short8 av0 = *(const short8*)(xs + swz(l15,      kb | (kq << 3)));
        const short8 av1 = *(const short8*)(xs + swz(16 + l15, kb | (kq << 3)));
        #pragma unroll
        for (int nf = 0; nf < 4; ++nf)
            acc[0][nf] = __builtin_amdgcn_mfma_f32_16x16x32_bf16(av0, bv[nf], acc[0][nf], 0, 0, 0);
        #pragma unroll
        for (int nf = 0; nf < 4; ++nf)
            acc[1][nf] = __builtin_amdgcn_mfma_f32_16x16x32_bf16(av1, bv[nf], acc[1][nf], 0, 0, 0);
        const int tn = t + 2;
        if (tn < NT) {
            if (tn < NKT1) {
                #pragma unroll
                for (int nf = 0; nf < 4; ++nf) bv[nf] = bp1[nf][tn << 2];
            } else {
                #pragma unroll
                for (int nf = 0; nf < 4; ++nf) bv[nf] = bp2[nf][(tn - NKT1) << 2];
            }
        }
    };
    #pragma unroll
    for (int tp = 0; tp < NT / 2; ++tp) {
        tile_step(2 * tp,     bv0);
        tile_step(2 * tp + 1, bv1);
    }

    // h2 = relu(acc) -> xs cols 0..255
    __syncthreads();
    #pragma unroll
    for (int mf = 0; mf < 2; ++mf)
        #pragma unroll
        for (int nf = 0; nf < 4; ++nf) {
            const int col  = nbase + nf * 16 + l15;
            const int row0 = mf * 16 + (kq << 2);
            #pragma unroll
            for (int r = 0; r < 4; ++r)
                xs[swz(row0 + r, col)] = f2b(fmaxf(acc[mf][nf][r], 0.0f));
        }
    __syncthreads();

    // layer 3 (256->3) + composite: 8 threads per pixel, shfl-reduce width 8
    {
        const int p = tid >> 3;
        const int j = tid & 7;
        float s0 = 0.f, s1 = 0.f, s2 = 0.f;
        #pragma unroll 4
        for (int i = 0; i < 32; ++i) {
            const int k = j * 32 + i;
            const float h = b2f(xs[swz(p, k)]);
            s0 += h * w3[k * 3 + 0];
            s1 += h * w3[k * 3 + 1];
            s2 += h * w3[k * 3 + 2];
        }
        #pragma unroll
        for (int off = 4; off; off >>= 1) {
            s0 += __shfl_down(s0, off, 8);
            s1 += __shfl_down(s1, off, 8);
            s2 += __shfl_down(s2, off, 8);
        }
        if (j == 0) {
            const int n = n0 + p;
            const int b = n >> 16;               // H*W = 65536
            const bool m = pix[n] > 0;
            float4 o4;
            o4.x = m ? (fmaxf(s0 + b3[0], 0.f) - 1.0f) : color_bg[b * 3 + 0];
            o4.y = m ? (fmaxf(s1 + b3[1], 0.f) - 1.0f) : color_bg[b * 3 + 1];
            o4.z = m ? (fmaxf(s2 + b3[2], 0.f) - 1.0f) : color_bg[b * 3 + 2];
            o4.w = m ? 1.0f : 0.0f;
            *(float4*)(out + (size_t)n * 4) = o4;
        }
    }
}

extern "C" void kernel_launch(void* const* d_in, const int* in_sizes, int n_in,
                              void* d_out, int out_size, void* d_ws, size_t ws_size,
                              hipStream_t stream) {
    const int*   pix      = (const int*)  d_in[0];
    const float* bary     = (const float*)d_in[1];
    const int*   faces    = (const int*)  d_in[2];
    const float* feature  = (const float*)d_in[3];
    const float* shapef   = (const float*)d_in[4];
    const float* color_bg = (const float*)d_in[5];
    const float* style    = (const float*)d_in[6];
    const float* w1       = (const float*)d_in[7];
    const float* b1       = (const float*)d_in[8];
    const float* w2       = (const float*)d_in[9];
    const float* b2       = (const float*)d_in[10];
    const float* w3       = (const float*)d_in[11];
    const float* b3       = (const float*)d_in[12];
    float* out = (float*)d_out;

    unsigned short* w1T = (unsigned short*)d_ws;              // 256*448 bf16
    unsigned short* w2T = w1T + 256 * 448;                    // 256*256 bf16
    float*          b1p = (float*)(w2T + 256 * 256);          // 256 f32

    hipLaunchKernelGGL(prep_weights, dim3(512), dim3(256), 0, stream,
                       style, w1, b1, w2, w1T, w2T, b1p);

    const int npix = in_sizes[0];                             // 262144
    hipLaunchKernelGGL(renderer_mfma, dim3(npix / TILE_M), dim3(256), 0, stream,
                       pix, bary, faces, feature, shapef, color_bg,
                       b2, w3, b3, w1T, w2T, b1p, out);
}

// Round 4
// 444.366 us; speedup vs baseline: 7.0655x; 1.0219x over previous
//
#include <hip/hip_runtime.h>
#include <math.h>

// DifferentiableMultiMLPRenderer — f16-MFMA fused renderer, round 4.
// style folded into b1 (K1 703->448); 1/3 blend scale folded into w1 rows k<384.
// Tables pre-converted to f16 in ws (gated on ws_size, f32 fallback path).
// TILE_M=32 px/block, 256 thr (4 waves, wave-tile 32x64). Weights streamed from
// global (L2-resident) with 3-deep register prefetch -> barrier-free K-loop.

typedef _Float16 hv8 __attribute__((ext_vector_type(8)));
typedef _Float16 hv4 __attribute__((ext_vector_type(4)));
typedef __attribute__((ext_vector_type(4))) float f32x4;

#define TILE_M 32
#define NKT1 14      // 448/32 layer-1 K-tiles
#define NKT2 8       // 256/32 layer-2 K-tiles
#define NT (NKT1 + NKT2)

// xs swizzle: 16B granules XOR'd by row&7 -> conflict-free ds_read_b128 at stride 448
__device__ inline int swz(int row, int k) {
    return row * 448 + ((((k >> 3) ^ (row & 7)) << 3) | (k & 7));
}

// ---- f32 -> f16 table conversion ----
__global__ __launch_bounds__(256)
void cvt_f16(const float* __restrict__ s, _Float16* __restrict__ d, int n) {
    const int n8 = n >> 3;
    const int step = gridDim.x * 256;
    for (int i = blockIdx.x * 256 + threadIdx.x; i < n8; i += step) {
        const float4 a = ((const float4*)s)[i * 2];
        const float4 b = ((const float4*)s)[i * 2 + 1];
        hv8 h = { (_Float16)a.x, (_Float16)a.y, (_Float16)a.z, (_Float16)a.w,
                  (_Float16)b.x, (_Float16)b.y, (_Float16)b.z, (_Float16)b.w };
        ((hv8*)d)[i] = h;
    }
    if (blockIdx.x == 0 && threadIdx.x == 0)
        for (int r = n8 << 3; r < n; ++r) d[r] = (_Float16)s[r];
}

// ---- prep: fold style into bias; build f16 transposed weights (1/3 folded) ----
__global__ __launch_bounds__(256)
void prep_weights(const float* __restrict__ style,
                  const float* __restrict__ w1, const float* __restrict__ b1,
                  const float* __restrict__ w2,
                  _Float16* __restrict__ w1T, _Float16* __restrict__ w2T,
                  float* __restrict__ b1p)
{
    const int j = blockIdx.x;
    const int t = threadIdx.x;
    if (j < 256) {
        float part = style[t] * w1[(size_t)(447 + t) * 256 + j];
        #pragma unroll
        for (int off = 32; off; off >>= 1) part += __shfl_down(part, off, 64);
        __shared__ float red[4];
        if ((t & 63) == 0) red[t >> 6] = part;
        __syncthreads();
        if (t == 0) b1p[j] = b1[j] + red[0] + red[1] + red[2] + red[3];
        for (int k = t; k < 448; k += 256) {
            float v = (k < 447) ? w1[(size_t)k * 256 + j] : 0.0f;
            if (k < 384) v *= (1.0f / 3.0f);
            w1T[(size_t)j * 448 + k] = (_Float16)v;
        }
    } else {
        const int jj = j - 256;
        w2T[(size_t)jj * 256 + t] = (_Float16)w2[(size_t)t * 256 + jj];
    }
}

// ---- main fused kernel ----
template<int TF16>
__global__ __launch_bounds__(256, 4)
void renderer_mfma(const int* __restrict__ pix, const float* __restrict__ bary,
                   const int* __restrict__ faces,
                   const float* __restrict__ featF, const float* __restrict__ shapeF,
                   const _Float16* __restrict__ featH, const _Float16* __restrict__ shapeH,
                   const float* __restrict__ color_bg,
                   const float* __restrict__ b2g,
                   const float* __restrict__ w3, const float* __restrict__ b3,
                   const _Float16* __restrict__ w1T,
                   const _Float16* __restrict__ w2T,
                   const float* __restrict__ b1p,
                   float* __restrict__ out)
{
    __shared__ _Float16 xs[TILE_M * 448];   // 28,672 B; h1/h2 overlay
    __shared__ int   vidx[TILE_M][3];
    __shared__ float bcs[TILE_M][3];

    const int tid  = threadIdx.x;
    const int cpx = gridDim.x >> 3;
    const int bid = (blockIdx.x & 7) * cpx + (blockIdx.x >> 3);   // XCD-aware
    const int n0  = bid * TILE_M;

    const int lane  = tid & 63;
    const int wv    = tid >> 6;
    const int nbase = wv << 6;
    const int l15   = lane & 15;
    const int kq    = lane >> 4;

    const hv8* bp1[4];
    const hv8* bp2[4];
    #pragma unroll
    for (int nf = 0; nf < 4; ++nf) {
        const int col = nbase + nf * 16 + l15;
        bp1[nf] = (const hv8*)(w1T + (size_t)col * 448 + (kq << 3));
        bp2[nf] = (const hv8*)(w2T + (size_t)col * 256 + (kq << 3));
    }
    hv8 bv[3][4];
    auto loadB = [&](int t, hv8* dst) {
        if (t < NKT1) {
            #pragma unroll
            for (int nf = 0; nf < 4; ++nf) dst[nf] = bp1[nf][t << 2];
        } else {
            #pragma unroll
            for (int nf = 0; nf < 4; ++nf) dst[nf] = bp2[nf][(t - NKT1) << 2];
        }
    };
    loadB(0, bv[0]);
    loadB(1, bv[1]);

    if (tid < TILE_M) {
        const int n = n0 + tid;
        const int face = pix[n];
        vidx[tid][0] = faces[face * 3 + 0];
        vidx[tid][1] = faces[face * 3 + 1];
        vidx[tid][2] = faces[face * 3 + 2];
        bcs[tid][0] = bary[n * 3 + 0];
        bcs[tid][1] = bary[n * 3 + 1];
        bcs[tid][2] = bary[n * 3 + 2];
    }
    __syncthreads();

    if (TF16) {
        // A1: feature -> xs[p][0..255], 8 f16/thread/iter
        {
            const int e8 = (tid & 31) << 3;
            const int pg = tid >> 5;
            #pragma unroll
            for (int pp = 0; pp < 4; ++pp) {
                const int p = (pp << 3) + pg;
                const int i0 = vidx[p][0], i1 = vidx[p][1], i2 = vidx[p][2];
                const _Float16 c0 = (_Float16)bcs[p][0], c1 = (_Float16)bcs[p][1], c2 = (_Float16)bcs[p][2];
                const hv8 f0 = *(const hv8*)(featH + (size_t)i0 * 256 + e8);
                const hv8 f1 = *(const hv8*)(featH + (size_t)i1 * 256 + e8);
                const hv8 f2 = *(const hv8*)(featH + (size_t)i2 * 256 + e8);
                *(hv8*)(&xs[swz(p, e8)]) = f0 * c0 + f1 * c1 + f2 * c2;
            }
        }
        // A2: shape -> xs[p][256..383]
        {
            const int e8 = (tid & 15) << 3;
            const int pg = tid >> 4;
            #pragma unroll
            for (int pp = 0; pp < 2; ++pp) {
                const int p = (pp << 4) + pg;
                const int i0 = vidx[p][0], i1 = vidx[p][1], i2 = vidx[p][2];
                const _Float16 c0 = (_Float16)bcs[p][0], c1 = (_Float16)bcs[p][1], c2 = (_Float16)bcs[p][2];
                const hv8 f0 = *(const hv8*)(shapeH + (size_t)i0 * 128 + e8);
                const hv8 f1 = *(const hv8*)(shapeH + (size_t)i1 * 128 + e8);
                const hv8 f2 = *(const hv8*)(shapeH + (size_t)i2 * 128 + e8);
                *(hv8*)(&xs[swz(p, 256 + e8)]) = f0 * c0 + f1 * c1 + f2 * c2;
            }
        }
    } else {
        // f32 fallback gather
        {
            const int c4 = (tid & 63) << 2;
            const int pg = tid >> 6;
            #pragma unroll
            for (int pp = 0; pp < 8; ++pp) {
                const int p = (pp << 2) + pg;
                const int i0 = vidx[p][0], i1 = vidx[p][1], i2 = vidx[p][2];
                const float c0 = bcs[p][0], c1 = bcs[p][1], c2 = bcs[p][2];
                const float4 f0 = *(const float4*)(featF + (size_t)i0 * 256 + c4);
                const float4 f1 = *(const float4*)(featF + (size_t)i1 * 256 + c4);
                const float4 f2 = *(const float4*)(featF + (size_t)i2 * 256 + c4);
                hv4 r = { (_Float16)(f0.x*c0 + f1.x*c1 + f2.x*c2),
                          (_Float16)(f0.y*c0 + f1.y*c1 + f2.y*c2),
                          (_Float16)(f0.z*c0 + f1.z*c1 + f2.z*c2),
                          (_Float16)(f0.w*c0 + f1.w*c1 + f2.w*c2) };
                *(hv4*)(&xs[swz(p, c4)]) = r;
            }
        }
        {
            const int c4 = (tid & 31) << 2;
            const int pg = tid >> 5;
            #pragma unroll
            for (int pp = 0; pp < 4; ++pp) {
                const int p = (pp << 3) + pg;
                const int i0 = vidx[p][0], i1 = vidx[p][1], i2 = vidx[p][2];
                const float c0 = bcs[p][0], c1 = bcs[p][1], c2 = bcs[p][2];
                const float4 f0 = *(const float4*)(shapeF + (size_t)i0 * 128 + c4);
                const float4 f1 = *(const float4*)(shapeF + (size_t)i1 * 128 + c4);
                const float4 f2 = *(const float4*)(shapeF + (size_t)i2 * 128 + c4);
                hv4 r = { (_Float16)(f0.x*c0 + f1.x*c1 + f2.x*c2),
                          (_Float16)(f0.y*c0 + f1.y*c1 + f2.y*c2),
                          (_Float16)(f0.z*c0 + f1.z*c1 + f2.z*c2),
                          (_Float16)(f0.w*c0 + f1.w*c1 + f2.w*c2) };
                *(hv4*)(&xs[swz(p, 256 + c4)]) = r;
            }
        }
    }
    // A3: NeRF embed -> xs[p][384..447] (slot 63 = 0), 8 vals/thread, one 16B store
    {
        const int p = tid >> 3;
        const int e = tid & 7;
        const float c0 = bcs[p][0], c1 = bcs[p][1], c2 = bcs[p][2];
        hv8 h;
        #pragma unroll
        for (int i = 0; i < 8; ++i) {
            const int s = e * 8 + i;
            float v;
            if (s < 3) v = (s == 0) ? c0 : ((s == 1) ? c1 : c2);
            else if (s < 63) {
                const int q = s - 3;
                const int f = q / 6;
                const int rem = q - f * 6;
                const int d = (rem >= 3) ? rem - 3 : rem;
                const float bd = (d == 0) ? c0 : ((d == 1) ? c1 : c2);
                const float arg = bd * (float)(1 << f);
                v = (rem < 3) ? __sinf(arg) : __cosf(arg);
            } else v = 0.0f;
            h[i] = (_Float16)v;
        }
        *(hv8*)(&xs[swz(p, 384 + e * 8)]) = h;
    }

    f32x4 acc[2][4];
    #pragma unroll
    for (int nf = 0; nf < 4; ++nf) {
        const float b = b1p[nbase + nf * 16 + l15];
        acc[0][nf] = (f32x4){b, b, b, b};
        acc[1][nf] = acc[0][nf];
    }
    __syncthreads();   // xs ready
    loadB(2, bv[2]);

    // barrier-free 22-tile K-loop, 3-deep register B-prefetch, fully unrolled
    #pragma unroll
    for (int t = 0; t < NT; ++t) {
        if (t == NKT1) {
            __syncthreads();   // layer-1 A-reads done
            #pragma unroll
            for (int mf = 0; mf < 2; ++mf)
                #pragma unroll
                for (int nf = 0; nf < 4; ++nf) {
                    const int col  = nbase + nf * 16 + l15;
                    const int row0 = mf * 16 + (kq << 2);
                    #pragma unroll
                    for (int r = 0; r < 4; ++r)
                        xs[swz(row0 + r, col)] = (_Float16)fmaxf(acc[mf][nf][r], 0.0f);
                    const float b = b2g[col];
                    acc[mf][nf] = (f32x4){b, b, b, b};
                }
            __syncthreads();   // h1 visible
        }
        const int kb = (t < NKT1) ? (t << 5) : ((t - NKT1) << 5);
        const hv8 av0 = *(const hv8*)(xs + swz(l15,      kb | (kq << 3)));
        const hv8 av1 = *(const hv8*)(xs + swz(16 + l15, kb | (kq << 3)));
        hv8* bvt = bv[t % 3];
        #pragma unroll
        for (int nf = 0; nf < 4; ++nf)
            acc[0][nf] = __builtin_amdgcn_mfma_f32_16x16x32_f16(av0, bvt[nf], acc[0][nf], 0, 0, 0);
        #pragma unroll
        for (int nf = 0; nf < 4; ++nf)
            acc[1][nf] = __builtin_amdgcn_mfma_f32_16x16x32_f16(av1, bvt[nf], acc[1][nf], 0, 0, 0);
        if (t + 3 < NT) loadB(t + 3, bv[t % 3]);
    }

    __syncthreads();
    #pragma unroll
    for (int mf = 0; mf < 2; ++mf)
        #pragma unroll
        for (int nf = 0; nf < 4; ++nf) {
            const int col  = nbase + nf * 16 + l15;
            const int row0 = mf * 16 + (kq << 2);
            #pragma unroll
            for (int r = 0; r < 4; ++r)
                xs[swz(row0 + r, col)] = (_Float16)fmaxf(acc[mf][nf][r], 0.0f);
        }
    __syncthreads();

    // layer 3 (256->3) + composite: 8 threads/pixel, vectorized
    {
        const int p = tid >> 3;
        const int j = tid & 7;
        float s0 = 0.f, s1 = 0.f, s2 = 0.f;
        #pragma unroll
        for (int i = 0; i < 4; ++i) {
            const int kb = j * 32 + i * 8;
            const hv8 hv = *(const hv8*)(&xs[swz(p, kb)]);
            const float* wp = w3 + (size_t)kb * 3;
            float wf[24];
            #pragma unroll
            for (int q = 0; q < 6; ++q) *(float4*)(wf + q * 4) = ((const float4*)wp)[q];
            #pragma unroll
            for (int q = 0; q < 8; ++q) {
                const float h = (float)hv[q];
                s0 += h * wf[q * 3 + 0];
                s1 += h * wf[q * 3 + 1];
                s2 += h * wf[q * 3 + 2];
            }
        }
        #pragma unroll
        for (int off = 4; off; off >>= 1) {
            s0 += __shfl_down(s0, off, 8);
            s1 += __shfl_down(s1, off, 8);
            s2 += __shfl_down(s2, off, 8);
        }
        if (j == 0) {
            const int n = n0 + p;
            const int b = n >> 16;               // H*W = 65536
            const bool m = pix[n] > 0;
            float4 o4;
            o4.x = m ? (fmaxf(s0 + b3[0], 0.f) - 1.0f) : color_bg[b * 3 + 0];
            o4.y = m ? (fmaxf(s1 + b3[1], 0.f) - 1.0f) : color_bg[b * 3 + 1];
            o4.z = m ? (fmaxf(s2 + b3[2], 0.f) - 1.0f) : color_bg[b * 3 + 2];
            o4.w = m ? 1.0f : 0.0f;
            *(float4*)(out + (size_t)n * 4) = o4;
        }
    }
}

extern "C" void kernel_launch(void* const* d_in, const int* in_sizes, int n_in,
                              void* d_out, int out_size, void* d_ws, size_t ws_size,
                              hipStream_t stream) {
    const int*   pix      = (const int*)  d_in[0];
    const float* bary     = (const float*)d_in[1];
    const int*   faces    = (const int*)  d_in[2];
    const float* feature  = (const float*)d_in[3];
    const float* shapef   = (const float*)d_in[4];
    const float* color_bg = (const float*)d_in[5];
    const float* style    = (const float*)d_in[6];
    const float* w1       = (const float*)d_in[7];
    const float* b1       = (const float*)d_in[8];
    const float* w2       = (const float*)d_in[9];
    const float* b2       = (const float*)d_in[10];
    const float* w3       = (const float*)d_in[11];
    const float* b3       = (const float*)d_in[12];
    float* out = (float*)d_out;

    const int nFeat  = in_sizes[3];
    const int nShape = in_sizes[4];

    char* ws = (char*)d_ws;
    _Float16* w1T = (_Float16*)ws;                          // 229,376 B
    _Float16* w2T = (_Float16*)(ws + 229376);               // 131,072 B
    float*    b1p = (float*)   (ws + 360448);               // 1,024 B
    _Float16* featH  = (_Float16*)(ws + 361472);
    _Float16* shapeH = featH + nFeat;
    const size_t need = 361472 + ((size_t)nFeat + (size_t)nShape) * 2;
    const bool full = ws_size >= need;

    if (full) {
        hipLaunchKernelGGL(cvt_f16, dim3(4096), dim3(256), 0, stream, feature, featH, nFeat);
        hipLaunchKernelGGL(cvt_f16, dim3(2048), dim3(256), 0, stream, shapef, shapeH, nShape);
    }
    hipLaunchKernelGGL(prep_weights, dim3(512), dim3(256), 0, stream,
                       style, w1, b1, w2, w1T, w2T, b1p);

    const int npix = in_sizes[0];                             // 262144
    if (full) {
        hipLaunchKernelGGL((renderer_mfma<1>), dim3(npix / TILE_M), dim3(256), 0, stream,
                           pix, bary, faces, feature, shapef, featH, shapeH, color_bg,
                           b2, w3, b3, w1T, w2T, b1p, out);
    } else {
        hipLaunchKernelGGL((renderer_mfma<0>), dim3(npix / TILE_M), dim3(256), 0, stream,
                           pix, bary, faces, feature, shapef, featH, shapeH, color_bg,
                           b2, w3, b3, w1T, w2T, b1p, out);
    }
}

// Round 5
// 319.014 us; speedup vs baseline: 9.8418x; 1.3929x over previous
//
#include <hip/hip_runtime.h>
#include <math.h>

// DifferentiableMultiMLPRenderer — f16-MFMA fused renderer, round 5.
// style folded into b1 (K1 703->448); 1/3 blend folded into w1 rows k<384.
// Tables pre-converted to f16 in ws. TILE_M=64 px/block, 256 thr, 4 waves,
// wave-tile 64x64 (acc[4][4]) -> 2x MFMA per load, half the weight traffic.
// A-frag ping-pong prefetch + 3-deep register B-prefetch; barrier-free K-loop.

typedef _Float16 hv8 __attribute__((ext_vector_type(8)));
typedef _Float16 hv4 __attribute__((ext_vector_type(4)));
typedef __attribute__((ext_vector_type(4))) float f32x4;

#define TILE_M 64
#define NKT1 14      // 448/32 layer-1 K-tiles
#define NKT2 8       // 256/32 layer-2 K-tiles
#define NT (NKT1 + NKT2)

// xs swizzle: 16B granules XOR'd by row&7 -> conflict-free ds_read_b128 at stride 448
__device__ inline int swz(int row, int k) {
    return row * 448 + ((((k >> 3) ^ (row & 7)) << 3) | (k & 7));
}

// ---- f32 -> f16 table conversion ----
__global__ __launch_bounds__(256)
void cvt_f16(const float* __restrict__ s, _Float16* __restrict__ d, int n) {
    const int n8 = n >> 3;
    const int step = gridDim.x * 256;
    for (int i = blockIdx.x * 256 + threadIdx.x; i < n8; i += step) {
        const float4 a = ((const float4*)s)[i * 2];
        const float4 b = ((const float4*)s)[i * 2 + 1];
        hv8 h = { (_Float16)a.x, (_Float16)a.y, (_Float16)a.z, (_Float16)a.w,
                  (_Float16)b.x, (_Float16)b.y, (_Float16)b.z, (_Float16)b.w };
        ((hv8*)d)[i] = h;
    }
    if (blockIdx.x == 0 && threadIdx.x == 0)
        for (int r = n8 << 3; r < n; ++r) d[r] = (_Float16)s[r];
}

// ---- prep: fold style into bias; build f16 transposed weights (1/3 folded) ----
__global__ __launch_bounds__(256)
void prep_weights(const float* __restrict__ style,
                  const float* __restrict__ w1, const float* __restrict__ b1,
                  const float* __restrict__ w2,
                  _Float16* __restrict__ w1T, _Float16* __restrict__ w2T,
                  float* __restrict__ b1p)
{
    const int j = blockIdx.x;
    const int t = threadIdx.x;
    if (j < 256) {
        float part = style[t] * w1[(size_t)(447 + t) * 256 + j];
        #pragma unroll
        for (int off = 32; off; off >>= 1) part += __shfl_down(part, off, 64);
        __shared__ float red[4];
        if ((t & 63) == 0) red[t >> 6] = part;
        __syncthreads();
        if (t == 0) b1p[j] = b1[j] + red[0] + red[1] + red[2] + red[3];
        for (int k = t; k < 448; k += 256) {
            float v = (k < 447) ? w1[(size_t)k * 256 + j] : 0.0f;
            if (k < 384) v *= (1.0f / 3.0f);
            w1T[(size_t)j * 448 + k] = (_Float16)v;
        }
    } else {
        const int jj = j - 256;
        w2T[(size_t)jj * 256 + t] = (_Float16)w2[(size_t)t * 256 + jj];
    }
}

// ---- main fused kernel ----
template<int TF16>
__global__ __launch_bounds__(256, 2)
void renderer_mfma(const int* __restrict__ pix, const float* __restrict__ bary,
                   const int* __restrict__ faces,
                   const float* __restrict__ featF, const float* __restrict__ shapeF,
                   const _Float16* __restrict__ featH, const _Float16* __restrict__ shapeH,
                   const float* __restrict__ color_bg,
                   const float* __restrict__ b2g,
                   const float* __restrict__ w3, const float* __restrict__ b3,
                   const _Float16* __restrict__ w1T,
                   const _Float16* __restrict__ w2T,
                   const float* __restrict__ b1p,
                   float* __restrict__ out)
{
    __shared__ _Float16 xs[TILE_M * 448];   // 57,344 B; h1/h2 overlay cols 0..255
    __shared__ int   vidx[TILE_M][3];
    __shared__ float bcs[TILE_M][3];

    const int tid  = threadIdx.x;
    const int cpx = gridDim.x >> 3;
    const int bid = (blockIdx.x & 7) * cpx + (blockIdx.x >> 3);   // XCD-aware
    const int n0  = bid * TILE_M;

    const int lane  = tid & 63;
    const int wv    = tid >> 6;
    const int nbase = wv << 6;           // each wave: all 64 rows x its 64 cols
    const int l15   = lane & 15;
    const int kq    = lane >> 4;

    const hv8* bp1[4];
    const hv8* bp2[4];
    #pragma unroll
    for (int nf = 0; nf < 4; ++nf) {
        const int col = nbase + nf * 16 + l15;
        bp1[nf] = (const hv8*)(w1T + (size_t)col * 448 + (kq << 3));
        bp2[nf] = (const hv8*)(w2T + (size_t)col * 256 + (kq << 3));
    }
    hv8 bv[3][4];
    auto loadB = [&](int t, hv8* dst) {
        if (t < NKT1) {
            #pragma unroll
            for (int nf = 0; nf < 4; ++nf) dst[nf] = bp1[nf][t << 2];
        } else {
            #pragma unroll
            for (int nf = 0; nf < 4; ++nf) dst[nf] = bp2[nf][(t - NKT1) << 2];
        }
    };
    loadB(0, bv[0]);
    loadB(1, bv[1]);

    if (tid < TILE_M) {
        const int n = n0 + tid;
        const int face = pix[n];
        vidx[tid][0] = faces[face * 3 + 0];
        vidx[tid][1] = faces[face * 3 + 1];
        vidx[tid][2] = faces[face * 3 + 2];
        bcs[tid][0] = bary[n * 3 + 0];
        bcs[tid][1] = bary[n * 3 + 1];
        bcs[tid][2] = bary[n * 3 + 2];
    }
    __syncthreads();

    if (TF16) {
        // A1: feature -> xs[p][0..255]; half-wave reads one 512B row per iter
        {
            const int e8 = (tid & 31) << 3;
            const int pg = tid >> 5;
            #pragma unroll
            for (int pp = 0; pp < 8; ++pp) {
                const int p = (pp << 3) + pg;
                const int i0 = vidx[p][0], i1 = vidx[p][1], i2 = vidx[p][2];
                const _Float16 c0 = (_Float16)bcs[p][0], c1 = (_Float16)bcs[p][1], c2 = (_Float16)bcs[p][2];
                const hv8 f0 = *(const hv8*)(featH + (size_t)i0 * 256 + e8);
                const hv8 f1 = *(const hv8*)(featH + (size_t)i1 * 256 + e8);
                const hv8 f2 = *(const hv8*)(featH + (size_t)i2 * 256 + e8);
                *(hv8*)(&xs[swz(p, e8)]) = f0 * c0 + f1 * c1 + f2 * c2;
            }
        }
        // A2: shape -> xs[p][256..383]
        {
            const int e8 = (tid & 15) << 3;
            const int pg = tid >> 4;
            #pragma unroll
            for (int pp = 0; pp < 4; ++pp) {
                const int p = (pp << 4) + pg;
                const int i0 = vidx[p][0], i1 = vidx[p][1], i2 = vidx[p][2];
                const _Float16 c0 = (_Float16)bcs[p][0], c1 = (_Float16)bcs[p][1], c2 = (_Float16)bcs[p][2];
                const hv8 f0 = *(const hv8*)(shapeH + (size_t)i0 * 128 + e8);
                const hv8 f1 = *(const hv8*)(shapeH + (size_t)i1 * 128 + e8);
                const hv8 f2 = *(const hv8*)(shapeH + (size_t)i2 * 128 + e8);
                *(hv8*)(&xs[swz(p, 256 + e8)]) = f0 * c0 + f1 * c1 + f2 * c2;
            }
        }
    } else {
        // f32 fallback gather
        {
            const int c4 = (tid & 63) << 2;
            const int pg = tid >> 6;
            #pragma unroll
            for (int pp = 0; pp < 16; ++pp) {
                const int p = (pp << 2) + pg;
                const int i0 = vidx[p][0], i1 = vidx[p][1], i2 = vidx[p][2];
                const float c0 = bcs[p][0], c1 = bcs[p][1], c2 = bcs[p][2];
                const float4 f0 = *(const float4*)(featF + (size_t)i0 * 256 + c4);
                const float4 f1 = *(const float4*)(featF + (size_t)i1 * 256 + c4);
                const float4 f2 = *(const float4*)(featF + (size_t)i2 * 256 + c4);
                hv4 r = { (_Float16)(f0.x*c0 + f1.x*c1 + f2.x*c2),
                          (_Float16)(f0.y*c0 + f1.y*c1 + f2.y*c2),
                          (_Float16)(f0.z*c0 + f1.z*c1 + f2.z*c2),
                          (_Float16)(f0.w*c0 + f1.w*c1 + f2.w*c2) };
                *(hv4*)(&xs[swz(p, c4)]) = r;
            }
        }
        {
            const int c4 = (tid & 31) << 2;
            const int pg = tid >> 5;
            #pragma unroll
            for (int pp = 0; pp < 8; ++pp) {
                const int p = (pp << 3) + pg;
                const int i0 = vidx[p][0], i1 = vidx[p][1], i2 = vidx[p][2];
                const float c0 = bcs[p][0], c1 = bcs[p][1], c2 = bcs[p][2];
                const float4 f0 = *(const float4*)(shapeF + (size_t)i0 * 128 + c4);
                const float4 f1 = *(const float4*)(shapeF + (size_t)i1 * 128 + c4);
                const float4 f2 = *(const float4*)(shapeF + (size_t)i2 * 128 + c4);
                hv4 r = { (_Float16)(f0.x*c0 + f1.x*c1 + f2.x*c2),
                          (_Float16)(f0.y*c0 + f1.y*c1 + f2.y*c2),
                          (_Float16)(f0.z*c0 + f1.z*c1 + f2.z*c2),
                          (_Float16)(f0.w*c0 + f1.w*c1 + f2.w*c2) };
                *(hv4*)(&xs[swz(p, 256 + c4)]) = r;
            }
        }
    }
    // A3: NeRF embed -> xs[p][384..447] (slot 63 = 0); 16 vals/thread, two 16B stores
    {
        const int p = tid >> 2;
        const int e16 = (tid & 3) << 4;
        const float c0 = bcs[p][0], c1 = bcs[p][1], c2 = bcs[p][2];
        #pragma unroll
        for (int hh = 0; hh < 2; ++hh) {
            hv8 h;
            #pragma unroll
            for (int i = 0; i < 8; ++i) {
                const int s = e16 + hh * 8 + i;
                float v;
                if (s < 3) v = (s == 0) ? c0 : ((s == 1) ? c1 : c2);
                else if (s < 63) {
                    const int q = s - 3;
                    const int f = q / 6;
                    const int rem = q - f * 6;
                    const int d = (rem >= 3) ? rem - 3 : rem;
                    const float bd = (d == 0) ? c0 : ((d == 1) ? c1 : c2);
                    const float arg = bd * (float)(1 << f);
                    v = (rem < 3) ? __sinf(arg) : __cosf(arg);
                } else v = 0.0f;
                h[i] = (_Float16)v;
            }
            *(hv8*)(&xs[swz(p, 384 + e16 + hh * 8)]) = h;
        }
    }

    f32x4 acc[4][4];
    #pragma unroll
    for (int nf = 0; nf < 4; ++nf) {
        const float b = b1p[nbase + nf * 16 + l15];
        #pragma unroll
        for (int mf = 0; mf < 4; ++mf) acc[mf][nf] = (f32x4){b, b, b, b};
    }
    __syncthreads();   // xs ready
    loadB(2, bv[2]);

    auto loadA = [&](int t, hv8* dst) {
        const int kb = ((t < NKT1) ? (t << 5) : ((t - NKT1) << 5)) | (kq << 3);
        #pragma unroll
        for (int mf = 0; mf < 4; ++mf)
            dst[mf] = *(const hv8*)(xs + swz(mf * 16 + l15, kb));
    };

    hv8 av[2][4];
    loadA(0, av[0]);

    // barrier-free 22-tile K-loop: A ping-pong prefetch + 3-deep B prefetch
    #pragma unroll
    for (int t = 0; t < NT; ++t) {
        if (t == NKT1) {
            __syncthreads();   // layer-1 A-reads done
            #pragma unroll
            for (int mf = 0; mf < 4; ++mf)
                #pragma unroll
                for (int nf = 0; nf < 4; ++nf) {
                    const int col  = nbase + nf * 16 + l15;
                    const int row0 = mf * 16 + (kq << 2);
                    #pragma unroll
                    for (int r = 0; r < 4; ++r)
                        xs[swz(row0 + r, col)] = (_Float16)fmaxf(acc[mf][nf][r], 0.0f);
                    const float b = b2g[col];
                    acc[mf][nf] = (f32x4){b, b, b, b};
                }
            __syncthreads();   // h1 visible
            loadA(t, av[t & 1]);
        }
        if (t + 1 < NT && t + 1 != NKT1) loadA(t + 1, av[(t + 1) & 1]);
        const hv8* avt = av[t & 1];
        const hv8* bvt = bv[t % 3];
        __builtin_amdgcn_s_setprio(1);
        #pragma unroll
        for (int mf = 0; mf < 4; ++mf)
            #pragma unroll
            for (int nf = 0; nf < 4; ++nf)
                acc[mf][nf] = __builtin_amdgcn_mfma_f32_16x16x32_f16(avt[mf], bvt[nf], acc[mf][nf], 0, 0, 0);
        __builtin_amdgcn_s_setprio(0);
        if (t + 3 < NT) loadB(t + 3, bv[t % 3]);
    }

    __syncthreads();
    #pragma unroll
    for (int mf = 0; mf < 4; ++mf)
        #pragma unroll
        for (int nf = 0; nf < 4; ++nf) {
            const int col  = nbase + nf * 16 + l15;
            const int row0 = mf * 16 + (kq << 2);
            #pragma unroll
            for (int r = 0; r < 4; ++r)
                xs[swz(row0 + r, col)] = (_Float16)fmaxf(acc[mf][nf][r], 0.0f);
        }
    __syncthreads();

    // layer 3 (256->3) + composite: 4 threads/pixel, shfl-reduce width 4
    {
        const int p = tid >> 2;
        const int j = tid & 3;
        float s0 = 0.f, s1 = 0.f, s2 = 0.f;
        #pragma unroll
        for (int i = 0; i < 8; ++i) {
            const int kb = j * 64 + i * 8;
            const hv8 hv = *(const hv8*)(&xs[swz(p, kb)]);
            const float* wp = w3 + (size_t)kb * 3;
            float wf[24];
            #pragma unroll
            for (int q = 0; q < 6; ++q) *(float4*)(wf + q * 4) = ((const float4*)wp)[q];
            #pragma unroll
            for (int q = 0; q < 8; ++q) {
                const float h = (float)hv[q];
                s0 += h * wf[q * 3 + 0];
                s1 += h * wf[q * 3 + 1];
                s2 += h * wf[q * 3 + 2];
            }
        }
        #pragma unroll
        for (int off = 2; off; off >>= 1) {
            s0 += __shfl_down(s0, off, 4);
            s1 += __shfl_down(s1, off, 4);
            s2 += __shfl_down(s2, off, 4);
        }
        if (j == 0) {
            const int n = n0 + p;
            const int b = n >> 16;               // H*W = 65536
            const bool m = pix[n] > 0;
            float4 o4;
            o4.x = m ? (fmaxf(s0 + b3[0], 0.f) - 1.0f) : color_bg[b * 3 + 0];
            o4.y = m ? (fmaxf(s1 + b3[1], 0.f) - 1.0f) : color_bg[b * 3 + 1];
            o4.z = m ? (fmaxf(s2 + b3[2], 0.f) - 1.0f) : color_bg[b * 3 + 2];
            o4.w = m ? 1.0f : 0.0f;
            *(float4*)(out + (size_t)n * 4) = o4;
        }
    }
}

extern "C" void kernel_launch(void* const* d_in, const int* in_sizes, int n_in,
                              void* d_out, int out_size, void* d_ws, size_t ws_size,
                              hipStream_t stream) {
    const int*   pix      = (const int*)  d_in[0];
    const float* bary     = (const float*)d_in[1];
    const int*   faces    = (const int*)  d_in[2];
    const float* feature  = (const float*)d_in[3];
    const float* shapef   = (const float*)d_in[4];
    const float* color_bg = (const float*)d_in[5];
    const float* style    = (const float*)d_in[6];
    const float* w1       = (const float*)d_in[7];
    const float* b1       = (const float*)d_in[8];
    const float* w2       = (const float*)d_in[9];
    const float* b2       = (const float*)d_in[10];
    const float* w3       = (const float*)d_in[11];
    const float* b3       = (const float*)d_in[12];
    float* out = (float*)d_out;

    const int nFeat  = in_sizes[3];
    const int nShape = in_sizes[4];

    char* ws = (char*)d_ws;
    _Float16* w1T = (_Float16*)ws;                          // 229,376 B
    _Float16* w2T = (_Float16*)(ws + 229376);               // 131,072 B
    float*    b1p = (float*)   (ws + 360448);               // 1,024 B
    _Float16* featH  = (_Float16*)(ws + 361472);
    _Float16* shapeH = featH + nFeat;
    const size_t need = 361472 + ((size_t)nFeat + (size_t)nShape) * 2;
    const bool full = ws_size >= need;

    if (full) {
        hipLaunchKernelGGL(cvt_f16, dim3(4096), dim3(256), 0, stream, feature, featH, nFeat);
        hipLaunchKernelGGL(cvt_f16, dim3(2048), dim3(256), 0, stream, shapef, shapeH, nShape);
    }
    hipLaunchKernelGGL(prep_weights, dim3(512), dim3(256), 0, stream,
                       style, w1, b1, w2, w1T, w2T, b1p);

    const int npix = in_sizes[0];                             // 262144
    if (full) {
        hipLaunchKernelGGL((renderer_mfma<1>), dim3(npix / TILE_M), dim3(256), 0, stream,
                           pix, bary, faces, feature, shapef, featH, shapeH, color_bg,
                           b2, w3, b3, w1T, w2T, b1p, out);
    } else {
        hipLaunchKernelGGL((renderer_mfma<0>), dim3(npix / TILE_M), dim3(256), 0, stream,
                           pix, bary, faces, feature, shapef, featH, shapeH, color_bg,
                           b2, w3, b3, w1T, w2T, b1p, out);
    }
}

// Round 6
// 249.951 us; speedup vs baseline: 12.5611x; 1.2763x over previous
//
#include <hip/hip_runtime.h>
#include <math.h>

// DifferentiableMultiMLPRenderer — round 6: per-vertex GEMM hoisting.
// P[v] = (feat[v]@W1a + shape[v]@W1b)/3 precomputed (pgemm). Pixel kernel:
// layer1 = blend(3 P-rows) + emb@W1e (K=64, 2 MFMA tiles) + b1' (style folded).
// Gather loads issued early into regs, consumed after MFMA tile 0 (T14).
// All LDS tiles 16B-granule XOR-swizzled: addr = row*STR + (k ^ ((row&7)<<3)).

typedef _Float16 hv8 __attribute__((ext_vector_type(8)));
typedef __attribute__((ext_vector_type(4))) float f32x4;

#define TILE_M 64

__device__ inline int swzE(int row, int k) { return row * 64  + (k ^ ((row & 7) << 3)); }
__device__ inline int swzH(int row, int k) { return row * 256 + (k ^ ((row & 7) << 3)); }
__device__ inline int swzA(int row, int k) { return row * 384 + (k ^ ((row & 7) << 3)); }

// ---- prep: fold style into bias; build f16 col-major w1/w2 (1/3 folded for k<384) ----
__global__ __launch_bounds__(256)
void prep_weights(const float* __restrict__ style,
                  const float* __restrict__ w1, const float* __restrict__ b1,
                  const float* __restrict__ w2,
                  _Float16* __restrict__ w1T, _Float16* __restrict__ w2T,
                  float* __restrict__ b1p)
{
    const int j = blockIdx.x;
    const int t = threadIdx.x;
    if (j < 256) {
        float part = style[t] * w1[(size_t)(447 + t) * 256 + j];
        #pragma unroll
        for (int off = 32; off; off >>= 1) part += __shfl_down(part, off, 64);
        __shared__ float red[4];
        if ((t & 63) == 0) red[t >> 6] = part;
        __syncthreads();
        if (t == 0) b1p[j] = b1[j] + red[0] + red[1] + red[2] + red[3];
        for (int k = t; k < 448; k += 256) {
            float v = (k < 447) ? w1[(size_t)k * 256 + j] : 0.0f;
            if (k < 384) v *= (1.0f / 3.0f);
            w1T[(size_t)j * 448 + k] = (_Float16)v;
        }
    } else {
        const int jj = j - 256;
        w2T[(size_t)jj * 256 + t] = (_Float16)w2[(size_t)t * 256 + jj];
    }
}

// ---- pgemm: P[v][j] = sum_k [feat|shape][v][k] * w1T[j][k] (1/3 already folded) ----
__global__ __launch_bounds__(256, 2)
void pgemm(const float* __restrict__ feat, const float* __restrict__ shp,
           const _Float16* __restrict__ w1T, _Float16* __restrict__ P, int nV)
{
    __shared__ _Float16 as[64 * 384];   // 48 KB
    const int tid = threadIdx.x;
    const int n0 = blockIdx.x * 64;
    const int lane = tid & 63, wv = tid >> 6;
    const int nbase = wv << 6, l15 = lane & 15, kq = lane >> 4;

    const hv8* bp[4];
    #pragma unroll
    for (int nf = 0; nf < 4; ++nf)
        bp[nf] = (const hv8*)(w1T + (size_t)(nbase + nf * 16 + l15) * 448 + (kq << 3));
    hv8 bv[3][4];
    auto loadB = [&](int t, hv8* dst) {
        #pragma unroll
        for (int nf = 0; nf < 4; ++nf) dst[nf] = bp[nf][t << 2];
    };
    loadB(0, bv[0]); loadB(1, bv[1]); loadB(2, bv[2]);

    // stage A: 64 rows x 384 f16 (12 chunks/thread)
    #pragma unroll
    for (int i = 0; i < 12; ++i) {
        const int id = tid + i * 256;
        const int row = id / 48;
        const int g = id - row * 48;
        int v = n0 + row; if (v >= nV) v = nV - 1;
        const float* s = (g < 32) ? (feat + (size_t)v * 256 + g * 8)
                                  : (shp  + (size_t)v * 128 + (g - 32) * 8);
        const float4 a = ((const float4*)s)[0];
        const float4 b = ((const float4*)s)[1];
        hv8 h = { (_Float16)a.x, (_Float16)a.y, (_Float16)a.z, (_Float16)a.w,
                  (_Float16)b.x, (_Float16)b.y, (_Float16)b.z, (_Float16)b.w };
        *(hv8*)(&as[swzA(row, g * 8)]) = h;
    }
    f32x4 acc[4][4];
    #pragma unroll
    for (int mf = 0; mf < 4; ++mf)
        #pragma unroll
        for (int nf = 0; nf < 4; ++nf) acc[mf][nf] = (f32x4){0.f, 0.f, 0.f, 0.f};
    __syncthreads();

    auto loadA = [&](int t, hv8* dst) {
        #pragma unroll
        for (int mf = 0; mf < 4; ++mf)
            dst[mf] = *(const hv8*)(as + swzA(mf * 16 + l15, (t << 5) | (kq << 3)));
    };
    hv8 av[2][4];
    loadA(0, av[0]);
    #pragma unroll
    for (int t = 0; t < 12; ++t) {
        if (t + 1 < 12) loadA(t + 1, av[(t + 1) & 1]);
        const hv8* avt = av[t & 1];
        const hv8* bvt = bv[t % 3];
        __builtin_amdgcn_s_setprio(1);
        #pragma unroll
        for (int mf = 0; mf < 4; ++mf)
            #pragma unroll
            for (int nf = 0; nf < 4; ++nf)
                acc[mf][nf] = __builtin_amdgcn_mfma_f32_16x16x32_f16(avt[mf], bvt[nf], acc[mf][nf], 0, 0, 0);
        __builtin_amdgcn_s_setprio(0);
        if (t + 3 < 12) loadB(t + 3, bv[t % 3]);
    }
    #pragma unroll
    for (int mf = 0; mf < 4; ++mf)
        #pragma unroll
        for (int nf = 0; nf < 4; ++nf) {
            const int col = nbase + nf * 16 + l15;
            const int r0 = mf * 16 + (kq << 2);
            #pragma unroll
            for (int r = 0; r < 4; ++r) {
                const int v = n0 + r0 + r;
                if (v < nV) P[(size_t)v * 256 + col] = (_Float16)acc[mf][nf][r];
            }
        }
}

// ---- main fused pixel kernel ----
__global__ __launch_bounds__(256, 2)
void renderer(const int* __restrict__ pix, const float* __restrict__ bary,
              const int* __restrict__ faces,
              const _Float16* __restrict__ P,
              const float* __restrict__ color_bg,
              const float* __restrict__ b2g,
              const float* __restrict__ w3, const float* __restrict__ b3,
              const _Float16* __restrict__ w1T,
              const _Float16* __restrict__ w2T,
              const float* __restrict__ b1p,
              float* __restrict__ out)
{
    __shared__ _Float16 embs[64 * 64];    // 8 KB
    __shared__ _Float16 pb[64 * 256];     // 32 KB: blend result; later h2
    __shared__ _Float16 h1s[64 * 256];    // 32 KB
    __shared__ int   vidx[TILE_M][3];
    __shared__ float bcs[TILE_M][3];

    const int tid = threadIdx.x;
    const int cpx = gridDim.x >> 3;
    const int bid = (blockIdx.x & 7) * cpx + (blockIdx.x >> 3);   // XCD-aware
    const int n0  = bid * TILE_M;

    const int lane  = tid & 63;
    const int wv    = tid >> 6;
    const int nbase = wv << 6;
    const int l15   = lane & 15;
    const int kq    = lane >> 4;

    // B pointers: emb cols of w1 (k=384..447) and w2
    const hv8* bpe[4];
    const hv8* bp2[4];
    #pragma unroll
    for (int nf = 0; nf < 4; ++nf) {
        const int col = nbase + nf * 16 + l15;
        bpe[nf] = (const hv8*)(w1T + (size_t)col * 448 + 384 + (kq << 3));
        bp2[nf] = (const hv8*)(w2T + (size_t)col * 256 + (kq << 3));
    }
    hv8 bve[2][4];
    #pragma unroll
    for (int nf = 0; nf < 4; ++nf) { bve[0][nf] = bpe[nf][0]; bve[1][nf] = bpe[nf][4]; }

    if (tid < TILE_M) {
        const int n = n0 + tid;
        const int face = pix[n];
        vidx[tid][0] = faces[face * 3 + 0];
        vidx[tid][1] = faces[face * 3 + 1];
        vidx[tid][2] = faces[face * 3 + 2];
        bcs[tid][0] = bary[n * 3 + 0];
        bcs[tid][1] = bary[n * 3 + 1];
        bcs[tid][2] = bary[n * 3 + 2];
    }
    __syncthreads();

    // issue all 24 P-row gathers early (consumed after MFMA tile 0)
    const int gp = tid >> 5;            // 0..7
    const int c8 = (tid & 31) << 3;     // col chunk
    hv8 g0[8], g1[8], g2[8];
    #pragma unroll
    for (int pp = 0; pp < 8; ++pp) {
        const int p = pp * 8 + gp;
        g0[pp] = *(const hv8*)(P + (size_t)vidx[p][0] * 256 + c8);
        g1[pp] = *(const hv8*)(P + (size_t)vidx[p][1] * 256 + c8);
        g2[pp] = *(const hv8*)(P + (size_t)vidx[p][2] * 256 + c8);
    }

    // emb (NeRF embed of bary) -> embs[p][0..63], slot 63 = 0
    {
        const int p = tid >> 2;
        const int e16 = (tid & 3) << 4;
        const float c0 = bcs[p][0], c1 = bcs[p][1], c2 = bcs[p][2];
        #pragma unroll
        for (int hh = 0; hh < 2; ++hh) {
            hv8 h;
            #pragma unroll
            for (int i = 0; i < 8; ++i) {
                const int s = e16 + hh * 8 + i;
                float v;
                if (s < 3) v = (s == 0) ? c0 : ((s == 1) ? c1 : c2);
                else if (s < 63) {
                    const int q = s - 3;
                    const int f = q / 6;
                    const int rem = q - f * 6;
                    const int d = (rem >= 3) ? rem - 3 : rem;
                    const float bd = (d == 0) ? c0 : ((d == 1) ? c1 : c2);
                    const float arg = bd * (float)(1 << f);
                    v = (rem < 3) ? __sinf(arg) : __cosf(arg);
                } else v = 0.0f;
                h[i] = (_Float16)v;
            }
            *(hv8*)(&embs[swzE(p, e16 + hh * 8)]) = h;
        }
    }

    f32x4 acc[4][4];
    #pragma unroll
    for (int nf = 0; nf < 4; ++nf) {
        const float b = b1p[nbase + nf * 16 + l15];
        #pragma unroll
        for (int mf = 0; mf < 4; ++mf) acc[mf][nf] = (f32x4){b, b, b, b};
    }
    __syncthreads();   // embs ready

    // layer-1 emb MFMA (2 tiles), blend interleaved between tiles
    hv8 ave[2][4];
    #pragma unroll
    for (int t = 0; t < 2; ++t)
        #pragma unroll
        for (int mf = 0; mf < 4; ++mf)
            ave[t][mf] = *(const hv8*)(embs + swzE(mf * 16 + l15, (t << 5) | (kq << 3)));

    __builtin_amdgcn_s_setprio(1);
    #pragma unroll
    for (int mf = 0; mf < 4; ++mf)
        #pragma unroll
        for (int nf = 0; nf < 4; ++nf)
            acc[mf][nf] = __builtin_amdgcn_mfma_f32_16x16x32_f16(ave[0][mf], bve[0][nf], acc[mf][nf], 0, 0, 0);
    __builtin_amdgcn_s_setprio(0);

    // blend gathered P rows -> pb
    #pragma unroll
    for (int pp = 0; pp < 8; ++pp) {
        const int p = pp * 8 + gp;
        const _Float16 c0 = (_Float16)bcs[p][0];
        const _Float16 c1 = (_Float16)bcs[p][1];
        const _Float16 c2 = (_Float16)bcs[p][2];
        *(hv8*)(&pb[swzH(p, c8)]) = g0[pp] * c0 + g1[pp] * c1 + g2[pp] * c2;
    }

    __builtin_amdgcn_s_setprio(1);
    #pragma unroll
    for (int mf = 0; mf < 4; ++mf)
        #pragma unroll
        for (int nf = 0; nf < 4; ++nf)
            acc[mf][nf] = __builtin_amdgcn_mfma_f32_16x16x32_f16(ave[1][mf], bve[1][nf], acc[mf][nf], 0, 0, 0);
    __builtin_amdgcn_s_setprio(0);

    hv8 bv2[3][4];
    auto loadB2 = [&](int t, hv8* dst) {
        #pragma unroll
        for (int nf = 0; nf < 4; ++nf) dst[nf] = bp2[nf][t << 2];
    };
    loadB2(0, bv2[0]); loadB2(1, bv2[1]); loadB2(2, bv2[2]);
    __syncthreads();   // pb ready

    // layer-1 epilogue: h1 = relu(acc + pb); re-init acc with b2
    #pragma unroll
    for (int mf = 0; mf < 4; ++mf)
        #pragma unroll
        for (int nf = 0; nf < 4; ++nf) {
            const int col = nbase + nf * 16 + l15;
            const int r0 = mf * 16 + (kq << 2);
            #pragma unroll
            for (int r = 0; r < 4; ++r) {
                const float pv = (float)pb[swzH(r0 + r, col)];
                h1s[swzH(r0 + r, col)] = (_Float16)fmaxf(acc[mf][nf][r] + pv, 0.0f);
            }
            const float b = b2g[col];
            acc[mf][nf] = (f32x4){b, b, b, b};
        }
    __syncthreads();   // h1 ready

    // layer-2: 8 K-tiles, A ping-pong + 3-deep B prefetch
    auto loadA2 = [&](int t, hv8* dst) {
        #pragma unroll
        for (int mf = 0; mf < 4; ++mf)
            dst[mf] = *(const hv8*)(h1s + swzH(mf * 16 + l15, (t << 5) | (kq << 3)));
    };
    hv8 av[2][4];
    loadA2(0, av[0]);
    #pragma unroll
    for (int t = 0; t < 8; ++t) {
        if (t + 1 < 8) loadA2(t + 1, av[(t + 1) & 1]);
        const hv8* avt = av[t & 1];
        const hv8* bvt = bv2[t % 3];
        __builtin_amdgcn_s_setprio(1);
        #pragma unroll
        for (int mf = 0; mf < 4; ++mf)
            #pragma unroll
            for (int nf = 0; nf < 4; ++nf)
                acc[mf][nf] = __builtin_amdgcn_mfma_f32_16x16x32_f16(avt[mf], bvt[nf], acc[mf][nf], 0, 0, 0);
        __builtin_amdgcn_s_setprio(0);
        if (t + 3 < 8) loadB2(t + 3, bv2[t % 3]);
    }
    __syncthreads();   // h1 reads done; reuse pb region for h2
    #pragma unroll
    for (int mf = 0; mf < 4; ++mf)
        #pragma unroll
        for (int nf = 0; nf < 4; ++nf) {
            const int col = nbase + nf * 16 + l15;
            const int r0 = mf * 16 + (kq << 2);
            #pragma unroll
            for (int r = 0; r < 4; ++r)
                pb[swzH(r0 + r, col)] = (_Float16)fmaxf(acc[mf][nf][r], 0.0f);
        }
    __syncthreads();

    // layer 3 (256->3) + composite: 4 threads/pixel
    {
        const int p = tid >> 2;
        const int j = tid & 3;
        float s0 = 0.f, s1 = 0.f, s2 = 0.f;
        #pragma unroll
        for (int i = 0; i < 8; ++i) {
            const int kb = j * 64 + i * 8;
            const hv8 hv = *(const hv8*)(&pb[swzH(p, kb)]);
            const float* wp = w3 + (size_t)kb * 3;
            float wf[24];
            #pragma unroll
            for (int q = 0; q < 6; ++q) *(float4*)(wf + q * 4) = ((const float4*)wp)[q];
            #pragma unroll
            for (int q = 0; q < 8; ++q) {
                const float h = (float)hv[q];
                s0 += h * wf[q * 3 + 0];
                s1 += h * wf[q * 3 + 1];
                s2 += h * wf[q * 3 + 2];
            }
        }
        #pragma unroll
        for (int off = 2; off; off >>= 1) {
            s0 += __shfl_down(s0, off, 4);
            s1 += __shfl_down(s1, off, 4);
            s2 += __shfl_down(s2, off, 4);
        }
        if (j == 0) {
            const int n = n0 + p;
            const int b = n >> 16;               // H*W = 65536
            const bool m = pix[n] > 0;
            float4 o4;
            o4.x = m ? (fmaxf(s0 + b3[0], 0.f) - 1.0f) : color_bg[b * 3 + 0];
            o4.y = m ? (fmaxf(s1 + b3[1], 0.f) - 1.0f) : color_bg[b * 3 + 1];
            o4.z = m ? (fmaxf(s2 + b3[2], 0.f) - 1.0f) : color_bg[b * 3 + 2];
            o4.w = m ? 1.0f : 0.0f;
            *(float4*)(out + (size_t)n * 4) = o4;
        }
    }
}

extern "C" void kernel_launch(void* const* d_in, const int* in_sizes, int n_in,
                              void* d_out, int out_size, void* d_ws, size_t ws_size,
                              hipStream_t stream) {
    const int*   pix      = (const int*)  d_in[0];
    const float* bary     = (const float*)d_in[1];
    const int*   faces    = (const int*)  d_in[2];
    const float* feature  = (const float*)d_in[3];
    const float* shapef   = (const float*)d_in[4];
    const float* color_bg = (const float*)d_in[5];
    const float* style    = (const float*)d_in[6];
    const float* w1       = (const float*)d_in[7];
    const float* b1       = (const float*)d_in[8];
    const float* w2       = (const float*)d_in[9];
    const float* b2       = (const float*)d_in[10];
    const float* w3       = (const float*)d_in[11];
    const float* b3       = (const float*)d_in[12];
    float* out = (float*)d_out;

    const int nV = in_sizes[3] / 256;                         // 50000 vertices

    char* ws = (char*)d_ws;
    _Float16* w1T = (_Float16*)ws;                            // 229,376 B
    _Float16* w2T = (_Float16*)(ws + 229376);                 // 131,072 B
    float*    b1p = (float*)   (ws + 360448);                 // 1,024 B
    _Float16* Ptab = (_Float16*)(ws + 361472);                // nV*256*2 = 25.6 MB

    hipLaunchKernelGGL(prep_weights, dim3(512), dim3(256), 0, stream,
                       style, w1, b1, w2, w1T, w2T, b1p);
    hipLaunchKernelGGL(pgemm, dim3((nV + 63) / 64), dim3(256), 0, stream,
                       feature, shapef, w1T, Ptab, nV);

    const int npix = in_sizes[0];                             // 262144
    hipLaunchKernelGGL(renderer, dim3(npix / TILE_M), dim3(256), 0, stream,
                       pix, bary, faces, Ptab, color_bg,
                       b2, w3, b3, w1T, w2T, b1p, out);
}